// Round 3
// baseline (689.706 us; speedup 1.0000x reference)
//
#include <hip/hip_runtime.h>
#include <cstdint>

typedef unsigned short u16;
typedef __attribute__((ext_vector_type(8))) short bf16x8;
typedef __attribute__((ext_vector_type(4))) float f32x4;

#define S_LEN 2048
#define DM    2048
#define NH    16
#define HDIM  128

__device__ __forceinline__ u16 f2bf(float f) {
  union { float f; unsigned u; } v; v.f = f;
  unsigned r = v.u + 0x7fffu + ((v.u >> 16) & 1u);
  return (u16)(r >> 16);
}
__device__ __forceinline__ float bf2f(u16 h) {
  union { unsigned u; float f; } v; v.u = ((unsigned)h) << 16;
  return v.f;
}

typedef __attribute__((address_space(3))) void lds_void_t;
typedef const __attribute__((address_space(1))) void gbl_void_t;
__device__ __forceinline__ void gload_lds16(const void* g, void* l) {
  __builtin_amdgcn_global_load_lds((gbl_void_t*)g, (lds_void_t*)l, 16, 0, 0);
}

// ---------------------------------------------------------------- convert
__global__ void cvt_k(const float* __restrict__ in, u16* __restrict__ out, int n) {
  int n4 = n >> 2;
  int stride = gridDim.x * blockDim.x;
  for (int i = blockIdx.x * blockDim.x + threadIdx.x; i < n4; i += stride) {
    float4 v = ((const float4*)in)[i];
    ushort4 o;
    o.x = f2bf(v.x); o.y = f2bf(v.y); o.z = f2bf(v.z); o.w = f2bf(v.w);
    ((ushort4*)out)[i] = o;
  }
}

// ---------------------------------------------------------------- GEMM  C = A (MxK) * B^T (B given as NxK row-major)
template <typename CT>
__global__ __launch_bounds__(256) void gemm_bt(const u16* __restrict__ A,
                                               const u16* __restrict__ Bm,
                                               CT* __restrict__ C,
                                               int M, int N, int K) {
  __shared__ u16 sA[128 * 32];
  __shared__ u16 sB[128 * 32];
  const int t = threadIdx.x;
  const int lane = t & 63, wid = t >> 6;
  const int r0 = lane & 15, kq = lane >> 4;
  const int wr = wid >> 1, wc = wid & 1;
  const long tile_m = (long)blockIdx.y * 128;
  const long tile_n = (long)blockIdx.x * 128;

  f32x4 acc[4][4];
#pragma unroll
  for (int i = 0; i < 4; ++i)
#pragma unroll
    for (int j = 0; j < 4; ++j)
      acc[i][j] = (f32x4){0.f, 0.f, 0.f, 0.f};

  const int rowA = t >> 2;
  const int colA = (t & 3) * 8;
  const u16* gA = A + (tile_m + rowA) * (long)K + colA;
  const u16* gB = Bm + (tile_n + rowA) * (long)K + colA;
  u16* lA = &sA[(wid * 16) * 32];
  u16* lB = &sB[(wid * 16) * 32];

  for (int k0 = 0; k0 < K; k0 += 32) {
    __syncthreads();
    gload_lds16(gA + k0, lA);
    gload_lds16(gA + k0 + 64 * (long)K, lA + 64 * 32);
    gload_lds16(gB + k0, lB);
    gload_lds16(gB + k0 + 64 * (long)K, lB + 64 * 32);
    __syncthreads();
    bf16x8 af[4], bfr[4];
#pragma unroll
    for (int i = 0; i < 4; ++i)
      af[i] = *(const bf16x8*)&sA[(wr * 64 + i * 16 + r0) * 32 + kq * 8];
#pragma unroll
    for (int i = 0; i < 4; ++i)
      bfr[i] = *(const bf16x8*)&sB[(wc * 64 + i * 16 + r0) * 32 + kq * 8];
#pragma unroll
    for (int i = 0; i < 4; ++i)
#pragma unroll
      for (int j = 0; j < 4; ++j)
        acc[i][j] = __builtin_amdgcn_mfma_f32_16x16x32_bf16(af[i], bfr[j], acc[i][j], 0, 0, 0);
  }

#pragma unroll
  for (int i = 0; i < 4; ++i)
#pragma unroll
    for (int j = 0; j < 4; ++j)
#pragma unroll
      for (int r = 0; r < 4; ++r) {
        long grow = tile_m + wr * 64 + i * 16 + kq * 4 + r;
        long gcol = tile_n + wc * 64 + j * 16 + r0;
        float v = acc[i][j][r];
        if constexpr (sizeof(CT) == 2) C[grow * N + gcol] = (CT)f2bf(v);
        else                           C[grow * N + gcol] = v;
      }
}

// ---------------------------------------------------------------- RoPE + reshape to (B,H,S,HD)
__global__ void rope_k(const u16* __restrict__ qkv, const float* __restrict__ cosT,
                       const float* __restrict__ sinT, u16* __restrict__ qt,
                       u16* __restrict__ kt) {
  int z = blockIdx.y;
  long idx = (long)blockIdx.x * blockDim.x + threadIdx.x;
  int hd2 = (int)(idx & 63);
  int s   = (int)((idx >> 6) & (S_LEN - 1));
  int bh  = (int)(idx >> 17);
  int b = bh >> 4, h = bh & 15;
  const u16* src = qkv + ((long)(b * S_LEN + s)) * 6144 + z * 2048 + h * HDIM + hd2 * 2;
  ushort2 p = *(const ushort2*)src;
  float e = bf2f(p.x), o = bf2f(p.y);
  float c = cosT[s * 64 + hd2], sn = sinT[s * 64 + hd2];
  float oe = e * c - o * sn;
  float oo = e * sn + o * c;
  u16* dst = (z ? kt : qt) + ((long)bh * S_LEN + s) * HDIM + hd2 * 2;
  ushort2 w; w.x = f2bf(oe); w.y = f2bf(oo);
  *(ushort2*)dst = w;
}

// ---------------------------------------------------------------- V transpose -> (B,H,HD,S)
__global__ void vtrans_k(const u16* __restrict__ qkv, u16* __restrict__ vt) {
  __shared__ u16 tile[64][65];
  int bh = blockIdx.z;
  int b = bh >> 4, h = bh & 15;
  int s0 = blockIdx.x * 64, d0 = blockIdx.y * 64;
  int tx = threadIdx.x, ty = threadIdx.y;
#pragma unroll
  for (int i = 0; i < 64; i += 4) {
    int s = s0 + ty + i;
    tile[ty + i][tx] = qkv[((long)(b * S_LEN + s)) * 6144 + 4096 + h * HDIM + d0 + tx];
  }
  __syncthreads();
#pragma unroll
  for (int i = 0; i < 64; i += 4) {
    int d = d0 + ty + i;
    vt[((long)bh * HDIM + d) * S_LEN + s0 + tx] = tile[tx][ty + i];
  }
}

// ---------------------------------------------------------------- flash attention v2 (causal)
// grid (32 qtiles of 64 rows, B*H), 4 waves x 16 q-rows each, KVBLK=64.
// Heavy tiles dispatched first (reverse tile order). No inter-wave sync needed.
__global__ __launch_bounds__(256, 4) void flash_k(const u16* __restrict__ qt,
                                                  const u16* __restrict__ kt,
                                                  const u16* __restrict__ vt,
                                                  u16* __restrict__ attn) {
  __shared__ u16 pbuf[4][16 * 64];  // per-wave 16x64 P tile, XOR-swizzled
  const int t = threadIdx.x, lane = t & 63, wid = t >> 6;
  const int r0 = lane & 15, kq = lane >> 4;
  const int bh = blockIdx.y, b = bh >> 4, h = bh & 15;
  const int tile = (gridDim.x - 1) - blockIdx.x;   // heavy-first
  const int q0w = tile * 64 + wid * 16;            // wave's first q row

  const u16* qb = qt + ((long)bh * S_LEN + q0w) * HDIM;
  const u16* kb = kt + (long)bh * S_LEN * HDIM;
  const u16* vb = vt + (long)bh * HDIM * S_LEN;
  u16* pb = &pbuf[wid][0];

  bf16x8 aq[4];
#pragma unroll
  for (int kk = 0; kk < 4; ++kk)
    aq[kk] = *(const bf16x8*)(qb + r0 * HDIM + kk * 32 + kq * 8);

  f32x4 o[8];
  float mrow[4], lrow[4];
#pragma unroll
  for (int dt = 0; dt < 8; ++dt) o[dt] = (f32x4){0.f, 0.f, 0.f, 0.f};
#pragma unroll
  for (int r = 0; r < 4; ++r) { mrow[r] = -1e30f; lrow[r] = 0.f; }

  const float sc = 0.08838834764831845f;  // 1/sqrt(128)
  const int myswz = (r0 & 7) << 3;

  for (int kv0 = 0; kv0 < q0w + 16; kv0 += 64) {
    // mask needed whenever the block's last column exceeds the wave's FIRST row
    const bool need_mask = (kv0 + 63 > q0w);

    f32x4 sacc[4];
#pragma unroll
    for (int kc = 0; kc < 4; ++kc) {
      bf16x8 bk[4];
#pragma unroll
      for (int kk = 0; kk < 4; ++kk)
        bk[kk] = *(const bf16x8*)(kb + (long)(kv0 + kc * 16 + r0) * HDIM + kk * 32 + kq * 8);
      f32x4 a = (f32x4){0.f, 0.f, 0.f, 0.f};
#pragma unroll
      for (int kk = 0; kk < 4; ++kk)
        a = __builtin_amdgcn_mfma_f32_16x16x32_bf16(aq[kk], bk[kk], a, 0, 0, 0);
      sacc[kc] = a;
    }

    float corr[4];
#pragma unroll
    for (int r = 0; r < 4; ++r) {
      int qrow = q0w + kq * 4 + r;
      float s0 = sacc[0][r] * sc, s1 = sacc[1][r] * sc;
      float s2 = sacc[2][r] * sc, s3 = sacc[3][r] * sc;
      if (need_mask) {
        if (kv0 +      r0 > qrow) s0 = -1e30f;
        if (kv0 + 16 + r0 > qrow) s1 = -1e30f;
        if (kv0 + 32 + r0 > qrow) s2 = -1e30f;
        if (kv0 + 48 + r0 > qrow) s3 = -1e30f;
      }
      float mx = fmaxf(fmaxf(s0, s1), fmaxf(s2, s3));
      mx = fmaxf(mx, __shfl_xor(mx, 1));
      mx = fmaxf(mx, __shfl_xor(mx, 2));
      mx = fmaxf(mx, __shfl_xor(mx, 4));
      mx = fmaxf(mx, __shfl_xor(mx, 8));
      float mnew = fmaxf(mrow[r], mx);
      float co = __expf(mrow[r] - mnew);
      mrow[r] = mnew;
      float p0 = __expf(s0 - mnew), p1 = __expf(s1 - mnew);
      float p2 = __expf(s2 - mnew), p3 = __expf(s3 - mnew);
      float rs = (p0 + p1) + (p2 + p3);
      rs += __shfl_xor(rs, 1);
      rs += __shfl_xor(rs, 2);
      rs += __shfl_xor(rs, 4);
      rs += __shfl_xor(rs, 8);
      lrow[r] = lrow[r] * co + rs;
      corr[r] = co;
      int row = kq * 4 + r;
      int swz = (row & 7) << 3;
      u16* prow = pb + row * 64;
      prow[(r0)      ^ swz] = f2bf(p0);
      prow[(16 + r0) ^ swz] = f2bf(p1);
      prow[(32 + r0) ^ swz] = f2bf(p2);
      prow[(48 + r0) ^ swz] = f2bf(p3);
    }
#pragma unroll
    for (int dt = 0; dt < 8; ++dt)
#pragma unroll
      for (int r = 0; r < 4; ++r)
        o[dt][r] *= corr[r];

#pragma unroll
    for (int c = 0; c < 2; ++c) {
      bf16x8 pa = *(const bf16x8*)&pb[(r0 * 64 + c * 32 + kq * 8) ^ myswz];
#pragma unroll
      for (int dt = 0; dt < 8; ++dt) {
        bf16x8 bv = *(const bf16x8*)(vb + (long)(dt * 16 + r0) * S_LEN + kv0 + c * 32 + kq * 8);
        o[dt] = __builtin_amdgcn_mfma_f32_16x16x32_bf16(pa, bv, o[dt], 0, 0, 0);
      }
    }
  }

  float inv[4];
#pragma unroll
  for (int r = 0; r < 4; ++r) inv[r] = 1.0f / lrow[r];
#pragma unroll
  for (int dt = 0; dt < 8; ++dt)
#pragma unroll
    for (int r = 0; r < 4; ++r) {
      int srow = q0w + kq * 4 + r;
      attn[((long)(b * S_LEN + srow)) * DM + h * HDIM + dt * 16 + r0] =
          f2bf(o[dt][r] * inv[r]);
    }
}

// ---------------------------------------------------------------- launch
extern "C" void kernel_launch(void* const* d_in, const int* in_sizes, int n_in,
                              void* d_out, int out_size, void* d_ws, size_t ws_size,
                              hipStream_t stream) {
  (void)in_sizes; (void)n_in; (void)out_size; (void)ws_size;
  const float* x  = (const float*)d_in[0];
  const float* fc = (const float*)d_in[2];
  const float* fs = (const float*)d_in[3];
  const float* wq = (const float*)d_in[5];
  const float* wk = (const float*)d_in[6];
  const float* wv = (const float*)d_in[7];
  const float* wo = (const float*)d_in[8];
  float* out = (float*)d_out;

  u16* xb   = (u16*)d_ws;            // 4096*2048
  u16* wqkv = xb + 8388608;          // 6144*2048
  u16* wob  = wqkv + 12582912;       // 2048*2048
  u16* qkv  = wob + 4194304;         // 4096*6144
  u16* qt   = qkv + 25165824;        // 32*2048*128
  u16* kt   = qt + 8388608;
  u16* vt   = kt + 8388608;
  u16* attn = qkv;                   // alias: qkv dead after rope/vtrans

  cvt_k<<<4096, 256, 0, stream>>>(x, xb, 8388608);
  cvt_k<<<2048, 256, 0, stream>>>(wq, wqkv, 4194304);
  cvt_k<<<2048, 256, 0, stream>>>(wk, wqkv + 4194304, 4194304);
  cvt_k<<<2048, 256, 0, stream>>>(wv, wqkv + 8388608, 4194304);
  cvt_k<<<2048, 256, 0, stream>>>(wo, wob, 4194304);

  gemm_bt<u16><<<dim3(48, 32), 256, 0, stream>>>(xb, wqkv, qkv, 4096, 6144, 2048);

  rope_k<<<dim3(16384, 2), 256, 0, stream>>>(qkv, fc, fs, qt, kt);
  vtrans_k<<<dim3(32, 2, 32), dim3(64, 4), 0, stream>>>(qkv, vt);

  flash_k<<<dim3(32, 32), 256, 0, stream>>>(qt, kt, vt, attn);

  gemm_bt<float><<<dim3(16, 32), 256, 0, stream>>>(attn, wob, out, 4096, 2048, 2048);
}